// Round 13
// baseline (576.095 us; speedup 1.0000x reference)
//
#include <hip/hip_runtime.h>

#define SEQ 4096
#define NBATCH 256

typedef _Float16 v2h __attribute__((ext_vector_type(2)));
typedef _Float16 h8  __attribute__((ext_vector_type(8)));
typedef __fp16   v2fp16 __attribute__((ext_vector_type(2)));

__device__ __forceinline__ float sqf(float v) { return v * v; }
__device__ __forceinline__ float fexp2(float v) { return __builtin_amdgcn_exp2f(v); }
__device__ __forceinline__ float frcp(float v)  { return __builtin_amdgcn_rcpf(v); }

#define L2E 1.4426950408889634f

// pack two floats -> fp16x2 (v_cvt_pkrtz_f16_f32), bit-cast to our v2h type
__device__ __forceinline__ v2h pkrtz(float a, float b) {
    v2fp16 r = __builtin_amdgcn_cvt_pkrtz(a, b);
    return __builtin_bit_cast(v2h, r);
}

__device__ __forceinline__ float fdot2f(v2h a, v2h b, float c) {
#if defined(__has_builtin) && __has_builtin(__builtin_amdgcn_fdot2)
    return __builtin_amdgcn_fdot2(a, b, c, false);
#else
    return fmaf((float)a.x, (float)b.x, fmaf((float)a.y, (float)b.y, c));
#endif
}

// order-preserving float<->uint key for atomicMax on floats
__device__ __forceinline__ unsigned fkey(float f) {
    const int b = __float_as_int(f);
    return (unsigned)(b ^ ((b >> 31) | 0x80000000));
}
__device__ __forceinline__ float fival(unsigned k) {
    const int b = (k & 0x80000000u) ? (int)(k ^ 0x80000000u) : (int)(~k);
    return __int_as_float(b);
}

// ---------------------------------------------------------------------------
// Kernel 0: fold the 24-wide input matvec into 12 inputs + bias, pre-scaled
// by the row's activation pre-scale (-log2e; -2log2e for g rows).
// Wp[d][r][16] = {w0..w11, bias, 0,0,0}  (r = torch row g*10+j). Inits MMu.
// ---------------------------------------------------------------------------
__global__ void wprep_kernel(
    const float* __restrict__ Wih_f, const float* __restrict__ bih_f,
    const float* __restrict__ bhh_f,
    const float* __restrict__ Wih_r, const float* __restrict__ bih_r,
    const float* __restrict__ bhh_r,
    float* __restrict__ Wp, unsigned* __restrict__ MMu)
{
    const int t = threadIdx.x;
    for (int i = t; i < NBATCH * 5; i += 256) MMu[i] = 0u;  // key 0 < any real
    if (t >= 80) return;
    const int d = t / 40, r = t % 40;
    const float* __restrict__ W  = (d ? Wih_r : Wih_f) + r * 24;
    const float* __restrict__ bi = d ? bih_r : bih_f;
    const float* __restrict__ bh = d ? bhh_r : bhh_f;
    const float sc = (r >= 20 && r < 30) ? (-2.f * L2E) : (-L2E);
    float o[13];
    o[0]  = W[0] + W[1] + W[2] + W[3];                // v4s
    o[1]  = W[4] + W[5] + W[6] + W[7];                // v5s
    o[2]  = W[4];                                     // v5p
    o[3]  = W[8] + W[9] + W[10] + W[11];              // v6s
    o[4]  = W[8] + W[9];                              // v6p
    o[5]  = W[12] + W[13] + W[14] + W[15];            // v7s
    o[6]  = W[12] + W[13] + W[14];                    // v7p
    o[7]  = W[16] + W[17] + W[18] + W[19];            // v8s+v8p
    o[8]  = W[20]; o[9] = W[21]; o[10] = W[22]; o[11] = W[23];   // x0..x3
    o[12] = bi[r] + bh[r];
    float* __restrict__ out = Wp + (d * 40 + r) * 16;
#pragma unroll
    for (int k = 0; k < 13; ++k) out[k] = o[k] * sc;
    out[13] = 0.f; out[14] = 0.f; out[15] = 0.f;
}

// tiny kernel: append conv taps to Wp (slots 1280..1309)
__global__ void taps_kernel(const float* __restrict__ w4p,
                            const float* __restrict__ w5p,
                            const float* __restrict__ w6p,
                            const float* __restrict__ w7p,
                            const float* __restrict__ w8p,
                            float* __restrict__ Wp)
{
    const int t = threadIdx.x;
    if (t < 4)  Wp[1280 + t] = w4p[t];
    else if (t < 9)  Wp[1280 + t] = w5p[t - 4];
    else if (t < 15) Wp[1280 + t] = w6p[t - 9];
    else if (t < 22) Wp[1280 + t] = w7p[t - 15];
    else if (t < 30) Wp[1280 + t] = w8p[t - 22];
}

// ---------------------------------------------------------------------------
// Kernel 1: per-batch conv max (atomicMax keys) + x transpose:
// xT[s][b][4] = x[b][4s..4s+3]  (scatter stores, fire-and-forget).
// 1024 blocks = (batch, quarter).
// ---------------------------------------------------------------------------
__global__ __launch_bounds__(256) void max_kernel(
    const float* __restrict__ x,
    const float* __restrict__ w4p, const float* __restrict__ w5p,
    const float* __restrict__ w6p, const float* __restrict__ w7p,
    const float* __restrict__ w8p,
    unsigned* __restrict__ MMu, float* __restrict__ xT)
{
    const int b    = blockIdx.x >> 2;
    const int quar = blockIdx.x & 3;
    const int tid  = threadIdx.x;
    const float* __restrict__ xr = x + (size_t)b * (4 * SEQ);

    float W4[4], W5[5], W6[6], W7[7], W8[8];
#pragma unroll
    for (int k = 0; k < 4; ++k) W4[k] = w4p[k];
#pragma unroll
    for (int k = 0; k < 5; ++k) W5[k] = w5p[k];
#pragma unroll
    for (int k = 0; k < 6; ++k) W6[k] = w6p[k];
#pragma unroll
    for (int k = 0; k < 7; ++k) W7[k] = w7p[k];
#pragma unroll
    for (int k = 0; k < 8; ++k) W8[k] = w8p[k];

    float m4 = -3.4e38f, m5 = -3.4e38f, m6 = -3.4e38f, m7 = -3.4e38f, m8 = -3.4e38f;
    for (int i = quar * (SEQ / 4) + tid; i < (quar + 1) * (SEQ / 4); i += 256) {
        const float4 t0 = *reinterpret_cast<const float4*>(xr + 4 * i);
        *reinterpret_cast<float4*>(xT + ((size_t)i * NBATCH + b) * 4) = t0;
        const float xa0 = t0.x, xa1 = t0.y, xa2 = t0.z, xa3 = t0.w;
        const float c4 = xa0 * W4[0] + xa1 * W4[1] + xa2 * W4[2] + xa3 * W4[3];
        m4 = fmaxf(m4, c4);
        if (i < SEQ - 1) {
            const float4 t1 = *reinterpret_cast<const float4*>(xr + 4 * i + 4);
            const float xa4 = t1.x, xa5 = t1.y, xa6 = t1.z, xa7 = t1.w;
            const float c5 = xa0*W5[0]+xa1*W5[1]+xa2*W5[2]+xa3*W5[3]+xa4*W5[4];
            const float c6 = xa0*W6[0]+xa1*W6[1]+xa2*W6[2]+xa3*W6[3]+xa4*W6[4]+xa5*W6[5];
            const float c7 = xa0*W7[0]+xa1*W7[1]+xa2*W7[2]+xa3*W7[3]+xa4*W7[4]+xa5*W7[5]+xa6*W7[6];
            const float c8 = xa0*W8[0]+xa1*W8[1]+xa2*W8[2]+xa3*W8[3]+xa4*W8[4]+xa5*W8[5]+xa6*W8[6]+xa7*W8[7];
            m5 = fmaxf(m5, c5); m6 = fmaxf(m6, c6);
            m7 = fmaxf(m7, c7); m8 = fmaxf(m8, c8);
        }
    }
#pragma unroll
    for (int off = 32; off; off >>= 1) {
        m4 = fmaxf(m4, __shfl_down(m4, off));
        m5 = fmaxf(m5, __shfl_down(m5, off));
        m6 = fmaxf(m6, __shfl_down(m6, off));
        m7 = fmaxf(m7, __shfl_down(m7, off));
        m8 = fmaxf(m8, __shfl_down(m8, off));
    }
    __shared__ float wr[4][5];
    if ((tid & 63) == 0) {
        const int w = tid >> 6;
        wr[w][0] = m4; wr[w][1] = m5; wr[w][2] = m6; wr[w][3] = m7; wr[w][4] = m8;
    }
    __syncthreads();
    if (tid < 5) {
        const float m = fmaxf(fmaxf(wr[0][tid], wr[1][tid]),
                              fmaxf(wr[2][tid], wr[3][tid]));
        atomicMax(&MMu[b * 5 + tid], fkey(m));
    }
}

// ---------------------------------------------------------------------------
// Kernel 2: conv winner-takes-all + full input-side gate preactivation for
// one direction, fp16, UNIT-MAJOR half-index (hidx = j*4+g), stored as 5
// dense planes gp[q][s'][b][8] (16 B/lane, perfectly coalesced both ways)
// + xs[s'][b]. s' mirrored for d=1. Reads xT coalesced; folded weights in
// LDS (broadcast ds_read_b128 — no in-loop s_load stream, r11's bug).
// Grid 4096 blocks (= s) x 256 thr (= b).
// ---------------------------------------------------------------------------
__global__ __launch_bounds__(256) void gprep_kernel(
    const float* __restrict__ xT,
    const unsigned* __restrict__ MMu,
    const float* __restrict__ Wp,
    _Float16* __restrict__ gp, float* __restrict__ xs, int d)
{
    const int s = blockIdx.x;
    const int b = threadIdx.x;

    __shared__ float wbuf[640];
    for (int i = b; i < 640; i += 256) wbuf[i] = Wp[d * 640 + i];
    __syncthreads();

    const float M4 = fival(MMu[b * 5 + 0]), M5 = fival(MMu[b * 5 + 1]),
                M6 = fival(MMu[b * 5 + 2]), M7 = fival(MMu[b * 5 + 3]),
                M8 = fival(MMu[b * 5 + 4]);

    float xw[12];
    if (s > 0) {
        const float4 t = *reinterpret_cast<const float4*>(
            xT + ((size_t)(s - 1) * NBATCH + b) * 4);
        xw[0] = t.x; xw[1] = t.y; xw[2] = t.z; xw[3] = t.w;
    } else { xw[0] = xw[1] = xw[2] = xw[3] = 0.f; }
    {
        const float4 t = *reinterpret_cast<const float4*>(
            xT + ((size_t)s * NBATCH + b) * 4);
        xw[4] = t.x; xw[5] = t.y; xw[6] = t.z; xw[7] = t.w;
    }
    if (s < SEQ - 1) {
        const float4 t = *reinterpret_cast<const float4*>(
            xT + ((size_t)(s + 1) * NBATCH + b) * 4);
        xw[8] = t.x; xw[9] = t.y; xw[10] = t.z; xw[11] = t.w;
    } else { xw[8] = xw[9] = xw[10] = xw[11] = 0.f; }

    const float* __restrict__ taps = Wp + 1280;  // [30]: w4(4) w5(5) w6(6) w7(7) w8(8)
    float c4s = 0.f, c5s = 0.f, c6s = 0.f, c7s = 0.f, c8s = 0.f;
    float c5p = 0.f, c6p = 0.f, c7p = 0.f, c8p = 0.f;
#pragma unroll
    for (int t = 0; t < 4; ++t) c4s += xw[4 + t] * taps[t];
#pragma unroll
    for (int t = 0; t < 5; ++t) { c5s += xw[4 + t] * taps[4 + t]; c5p += xw[t] * taps[4 + t]; }
#pragma unroll
    for (int t = 0; t < 6; ++t) { c6s += xw[4 + t] * taps[9 + t]; c6p += xw[t] * taps[9 + t]; }
#pragma unroll
    for (int t = 0; t < 7; ++t) { c7s += xw[4 + t] * taps[15 + t]; c7p += xw[t] * taps[15 + t]; }
#pragma unroll
    for (int t = 0; t < 8; ++t) { c8s += xw[4 + t] * taps[22 + t]; c8p += xw[t] * taps[22 + t]; }

    const bool oks = (s < SEQ - 1);
    const bool okp = (s > 0);
    const float v4s = sqf(c4s + M4);
    const float v5s = oks ? sqf(c5s + M5) : 0.f;
    const float v6s = oks ? sqf(c6s + M6) : 0.f;
    const float v7s = oks ? sqf(c7s + M7) : 0.f;
    const float v8s = oks ? sqf(c8s + M8) : 0.f;
    const float v5p = okp ? sqf(c5p + M5) : 0.f;
    const float v6p = okp ? sqf(c6p + M6) : 0.f;
    const float v7p = okp ? sqf(c7p + M7) : 0.f;
    const float v8p = okp ? sqf(c8p + M8) : 0.f;

    float vv[12];
    vv[0] = v4s; vv[1] = v5s; vv[2]  = v5p;   vv[3]  = v6s;
    vv[4] = v6p; vv[5] = v7s; vv[6]  = v7p;   vv[7]  = v8s + v8p;
    vv[8] = xw[4]; vv[9] = xw[5]; vv[10] = xw[6]; vv[11] = xw[7];

    const int sp = d ? (SEQ - 1 - s) : s;
    xs[(size_t)sp * NBATCH + b] = (xw[4] + xw[5]) + (xw[6] + xw[7]);

    float er[40];   // unit-major: er[rr], rr = j*4+g -> torch row (rr&3)*10+(rr>>2)
#pragma unroll
    for (int rr = 0; rr < 40; ++rr) {
        const int row = (rr & 3) * 10 + (rr >> 2);
        const float4 w0 = *reinterpret_cast<const float4*>(&wbuf[row * 16 + 0]);
        const float4 w1 = *reinterpret_cast<const float4*>(&wbuf[row * 16 + 4]);
        const float4 w2 = *reinterpret_cast<const float4*>(&wbuf[row * 16 + 8]);
        const float  bb = wbuf[row * 16 + 12];
        float a0 = bb, a1 = 0.f, a2 = 0.f, a3 = 0.f;
        a0 = fmaf(vv[0], w0.x, a0);  a1 = fmaf(vv[1], w0.y, a1);
        a2 = fmaf(vv[2], w0.z, a2);  a3 = fmaf(vv[3], w0.w, a3);
        a0 = fmaf(vv[4], w1.x, a0);  a1 = fmaf(vv[5], w1.y, a1);
        a2 = fmaf(vv[6], w1.z, a2);  a3 = fmaf(vv[7], w1.w, a3);
        a0 = fmaf(vv[8], w2.x, a0);  a1 = fmaf(vv[9], w2.y, a1);
        a2 = fmaf(vv[10], w2.z, a2); a3 = fmaf(vv[11], w2.w, a3);
        er[rr] = (a0 + a1) + (a2 + a3);
    }
    const size_t PS = (size_t)SEQ * NBATCH;        // plane stride in h8 units
    h8* __restrict__ gq = reinterpret_cast<h8*>(gp);
#pragma unroll
    for (int q = 0; q < 5; ++q) {
        h8 o;
#pragma unroll
        for (int e = 0; e < 8; ++e) o[e] = (_Float16)er[q * 8 + e];
        gq[q * PS + (size_t)sp * NBATCH + b] = o;
    }
}

// ---------------------------------------------------------------------------
// Kernel 3: lane=chain LSTM, fp16 dot2 recurrence. One direction.
// Grid = 256 segs x 4 bgroups = 1024 blocks x 64 thr = 1 wave/SIMD.
// Whh packed fp16x2 -> 200 VGPRs (fits the 256-ArchVGPR cap: r11's spill
// fixed). h carried fp16-packed (pkrtz); cs fp32; preacts fp32 from
// coalesced plane loads. Segs 0..3 start at s=0 with exact short history;
// segs >=4 warm up 64 steps from 0 (validated absmax 0.0 r5-r11).
// ---------------------------------------------------------------------------
__global__ __launch_bounds__(64, 1) void lstm_kernel(
    const _Float16* __restrict__ gp,
    const float* __restrict__ xs,
    const float* __restrict__ Whh,
    float* __restrict__ P)
{
    const int seg  = blockIdx.x >> 2;          // 0..255
    const int bg   = blockIdx.x & 3;
    const int lane = threadIdx.x;
    const int b    = bg * 64 + lane;

    int sStart = seg * 16 - 64;
    int warm   = 64;
    if (sStart < 0) { warm = seg * 16; sStart = 0; }
    const int L = warm + 16;

    // packed recurrent weights: w2[rr*5+k2], rr = j*4+g (unit-major)
    v2h w2[200];
#pragma unroll
    for (int j = 0; j < 10; ++j)
#pragma unroll
        for (int g = 0; g < 4; ++g) {
            const float sc = (g == 2) ? (-2.f * L2E) : (-L2E);
            const float* wr = Whh + (g * 10 + j) * 10;
#pragma unroll
            for (int k2 = 0; k2 < 5; ++k2)
                w2[(j * 4 + g) * 5 + k2] =
                    pkrtz(wr[2 * k2] * sc, wr[2 * k2 + 1] * sc);
        }

    const size_t PS = (size_t)SEQ * NBATCH;
    const h8* __restrict__ gq = reinterpret_cast<const h8*>(gp);
    const size_t i0 = (size_t)sStart * NBATCH + b;

    h8 cur[5], nxt[5];
#pragma unroll
    for (int q = 0; q < 5; ++q) cur[q] = gq[q * PS + i0];
#pragma unroll
    for (int q = 0; q < 5; ++q) nxt[q] = gq[q * PS + i0 + NBATCH];
    float xc = xs[i0];
    float xn = xs[i0 + NBATCH];

    v2h h2[5];
#pragma unroll
    for (int k = 0; k < 5; ++k) h2[k] = (v2h){(_Float16)0.f, (_Float16)0.f};
    float cs[10];
#pragma unroll
    for (int j = 0; j < 10; ++j) cs[j] = 0.f;
    float accS = 0.f;

    for (int t = 0; t < L; ++t) {
        float hn[10], hsum = 0.f;
#pragma unroll
        for (int j = 0; j < 10; ++j) {
            float e[4];
#pragma unroll
            for (int g = 0; g < 4; ++g) {
                const int hidx = j * 4 + g;
                float ea = fdot2f(h2[0], w2[hidx * 5 + 0],
                                  (float)cur[hidx >> 3][hidx & 7]);
                float eb = fdot2f(h2[1], w2[hidx * 5 + 1], 0.f);
                ea = fdot2f(h2[2], w2[hidx * 5 + 2], ea);
                eb = fdot2f(h2[3], w2[hidx * 5 + 3], eb);
                ea = fdot2f(h2[4], w2[hidx * 5 + 4], ea);
                e[g] = ea + eb;
            }
            const float ig = frcp(1.f + fexp2(e[0]));
            const float fg = frcp(1.f + fexp2(e[1]));
            const float tg = fmaf(frcp(1.f + fexp2(e[2])), 2.f, -1.f);
            const float og = frcp(1.f + fexp2(e[3]));
            cs[j] = fmaf(fg, cs[j], (ig * (-2.f * L2E)) * tg);   // cs=-2L2E*c
            hn[j] = og * fmaf(2.f, frcp(1.f + fexp2(cs[j])), -1.f);
            hsum += hn[j];
        }
        accS = fmaf(xc, hsum, accS);
#pragma unroll
        for (int k = 0; k < 5; ++k) h2[k] = pkrtz(hn[2 * k], hn[2 * k + 1]);
        // rotate prefetch (depth 1)
#pragma unroll
        for (int q = 0; q < 5; ++q) cur[q] = nxt[q];
        xc = xn;
        {
            const int tn = (t + 2 < L) ? t + 2 : L - 1;
            const size_t ii = i0 + (size_t)tn * NBATCH;
#pragma unroll
            for (int q = 0; q < 5; ++q) nxt[q] = gq[q * PS + ii];
            xn = xs[ii];
        }
        if (t + 1 == warm) accS = 0.f;         // drop warmup contributions
    }

    P[seg * NBATCH + b] = accS;
}

// ---------------------------------------------------------------------------
// Kernel 4: out[b] = sigmoid( sum over 2 dirs x 256 segments )
// ---------------------------------------------------------------------------
__global__ __launch_bounds__(256) void final_kernel(const float* __restrict__ P,
                                                    float* __restrict__ out)
{
    const int b = threadIdx.x;
    float v = 0.f;
    for (int i = 0; i < 512; ++i) v += P[(size_t)i * NBATCH + b];
    out[b] = frcp(1.f + fexp2(-v * L2E));
}

extern "C" void kernel_launch(void* const* d_in, const int* in_sizes, int n_in,
                              void* d_out, int out_size, void* d_ws, size_t ws_size,
                              hipStream_t stream)
{
    const float* x     = (const float*)d_in[0];
    const float* w4    = (const float*)d_in[1];
    const float* w5    = (const float*)d_in[2];
    const float* w6    = (const float*)d_in[3];
    const float* w7    = (const float*)d_in[4];
    const float* w8    = (const float*)d_in[5];
    const float* Wih_f = (const float*)d_in[6];
    const float* Whh_f = (const float*)d_in[7];
    const float* bih_f = (const float*)d_in[8];
    const float* bhh_f = (const float*)d_in[9];
    const float* Wih_r = (const float*)d_in[10];
    const float* Whh_r = (const float*)d_in[11];
    const float* bih_r = (const float*)d_in[12];
    const float* bhh_r = (const float*)d_in[13];

    // ws: gp fp16 5 planes [4096][256][8] (83.9MB, reused per dir)
    //   | xT fp32 [4096][256][4] (16.8MB) | xs fp32 [4096][256] (4.2MB)
    //   | P [2][256][256] (0.5MB) | MMu[1280] | Wp[1280+32]   ~105.5 MB
    _Float16* gp  = (_Float16*)d_ws;
    float*    xT  = (float*)(gp + (size_t)5 * SEQ * NBATCH * 8);
    float*    xs  = xT + (size_t)SEQ * NBATCH * 4;
    float*    P   = xs + (size_t)SEQ * NBATCH;
    unsigned* MMu = (unsigned*)(P + 2 * 256 * NBATCH);
    float*    Wpp = (float*)(MMu + 1280);

    wprep_kernel<<<1, 256, 0, stream>>>(Wih_f, bih_f, bhh_f,
                                        Wih_r, bih_r, bhh_r, Wpp, MMu);
    taps_kernel<<<1, 32, 0, stream>>>(w4, w5, w6, w7, w8, Wpp);
    max_kernel<<<4 * NBATCH, 256, 0, stream>>>(x, w4, w5, w6, w7, w8, MMu, xT);
    // forward
    gprep_kernel<<<SEQ, 256, 0, stream>>>(xT, MMu, Wpp, gp, xs, 0);
    lstm_kernel<<<1024, 64, 0, stream>>>(gp, xs, Whh_f, P);
    // reverse (reuses gp/xs; stream-ordered)
    gprep_kernel<<<SEQ, 256, 0, stream>>>(xT, MMu, Wpp, gp, xs, 1);
    lstm_kernel<<<1024, 64, 0, stream>>>(gp, xs, Whh_r, P + 256 * NBATCH);
    final_kernel<<<1, NBATCH, 0, stream>>>(P, (float*)d_out);
}